// Round 13
// baseline (864.345 us; speedup 1.0000x reference)
//
#include <hip/hip_runtime.h>
#include <math.h>

// Problem constants (from reference)
#define NROWS 18432
#define IN_DIM 1024
#define HID_DIM 4096
#define OUT_DIM 4096
#define NTN 16   // 4096/256 column tiles (both layers)

typedef __attribute__((ext_vector_type(8))) short bf16x8;
typedef __attribute__((ext_vector_type(4))) float f32x4;

typedef const __attribute__((address_space(1))) char gchar;
typedef __attribute__((address_space(3))) char lchar;

__device__ __forceinline__ unsigned short f2bf(float f) {
    union { float f; unsigned u; } v; v.f = f;
    unsigned r = v.u + 0x7fffu + ((v.u >> 16) & 1u);  // RNE
    return (unsigned short)(r >> 16);
}

__device__ __forceinline__ f32x4 MFMA16(bf16x8 a, bf16x8 b, f32x4 c) {
    return __builtin_amdgcn_mfma_f32_16x16x32_bf16(a, b, c, 0, 0, 0);
}

// ---------------- conversion kernels ----------------

__global__ void cvt_f32_bf16_k(const float4* __restrict__ in, uint4* __restrict__ out, int nvec) {
    int i = blockIdx.x * blockDim.x + threadIdx.x;
    if (i >= nvec) return;
    float4 a = in[2 * i], b = in[2 * i + 1];
    union { unsigned short s[8]; uint4 v; } o;
    o.s[0] = f2bf(a.x); o.s[1] = f2bf(a.y); o.s[2] = f2bf(a.z); o.s[3] = f2bf(a.w);
    o.s[4] = f2bf(b.x); o.s[5] = f2bf(b.y); o.s[6] = f2bf(b.z); o.s[7] = f2bf(b.w);
    out[i] = o.v;
}

// int8 values harness-materialized as int32; exact in bf16
__global__ void cvt_i32_bf16_k(const int4* __restrict__ in, uint4* __restrict__ out, int nvec) {
    int i = blockIdx.x * blockDim.x + threadIdx.x;
    if (i >= nvec) return;
    int4 a = in[2 * i], b = in[2 * i + 1];
    union { unsigned short s[8]; uint4 v; } o;
    o.s[0] = f2bf((float)a.x); o.s[1] = f2bf((float)a.y);
    o.s[2] = f2bf((float)a.z); o.s[3] = f2bf((float)a.w);
    o.s[4] = f2bf((float)b.x); o.s[5] = f2bf((float)b.y);
    o.s[6] = f2bf((float)b.z); o.s[7] = f2bf((float)b.w);
    out[i] = o.v;
}

// ------ 256x256 GEMM, BK=32, 4-BUFFER rotation, full-latency staging, 1 barrier/K-tile ------
// 8 waves (2Mx4N), per-wave 128x64 out. LDS = 4 bufs x 32KB (A 16KB + B 16KB), tile t -> buf t&3.
// Iter t stages the ENTIRE tile t+2 (4x 8KB units, 1 gload/thread each): every unit has >=4
// phases (~2500+ cyc) of HBM-latency cover -- R10/R12 staged tile 2j+1 only 2-3 phases ahead of
// consumption, stalling the vmcnt every other tile. ONE trailing {vmcnt(4) -> s_barrier} per
// K-tile guarantees tile t+1 collectively (newest-4 outstanding = this iter's own 4 stages;
// VMEM retires in order). Tail (no stage): vmcnt(0). WAR: stages hit buf(t-2), whose reads
// completed >=2 barriers earlier. K-tile split into TWO MFMA clusters with the A-hi reads
// between them: m0-cluster (16 MFMA) executes while A-hi reads complete (per-wave LDS||MFMA
// overlap, zero extra regs -- aq reused for lo/hi since m0 MFMAs precede the overwrite).
// Swizzle: R8's proven 0-conflict 64B-row mapping (byte ^= ((row>>1)&3)<<4) on stage src + reads.
// T1 XCD swizzle, T5 setprio. EPI==0: bf16 gelu(acc*sc+bi); EPI==1: f32 acc*sc+bi. C stride 4096.
template<int EPI>
__global__ __launch_bounds__(512, 2)
void gemm4b(const unsigned short* __restrict__ A, const unsigned short* __restrict__ B,
            const float* __restrict__ scale, const float* __restrict__ bias,
            void* __restrict__ Cout, int K) {
    extern __shared__ __align__(16) char sm[];   // 131072 bytes dynamic (4 x 32KB)

    const int tid  = threadIdx.x;
    const int lane = tid & 63;
    const int wid  = tid >> 6;
    const int wm   = wid >> 2, wn = wid & 3;

    // T1: bijective XCD swizzle (m204)
    const int nwg  = gridDim.x;
    const int q    = nwg >> 3, r = nwg & 7;
    const int xcd  = blockIdx.x & 7, bidx = blockIdx.x >> 3;
    const int swz  = xcd * q + (xcd < r ? xcd : r) + bidx;
    const int tm   = swz / NTN, tn = swz % NTN;

    const size_t rowbytes = (size_t)K * 2;
    const char* Ag = (const char*)A + (size_t)tm * 256 * rowbytes;
    const char* Bg = (const char*)B + (size_t)tn * 256 * rowbytes;

    const int l16 = lane & 15;
    const int cg  = (lane >> 4) << 4;   // 16-B col slot within 64-B row

    f32x4  acc[8][4] = {};
    bf16x8 aq[4], b0[2], b1[2];

    const int NT = K >> 5;

// Stage one 8KB unit (UNIT 0: rows 0-127, 1: rows 128-255) of a 256x32bf16 half (A or B).
// LDS dest linear (1 gload/thread); global source pre-inverse-swizzled (rule 21). R8-proven.
#define STAGE(GB, LB, UNIT, KTB) { \
    const int po_ = ((UNIT) << 13) + (tid << 4); \
    const int r_  = po_ >> 6; \
    const int b_  = (po_ & 63) ^ (((r_ >> 1) & 3) << 4); \
    __builtin_amdgcn_global_load_lds( \
        (gchar*)((GB) + (size_t)r_ * rowbytes + (KTB) + (size_t)b_), \
        (lchar*)((LB) + po_), 16, 0, 0); \
}

// swizzled read address for (row, col-slot cg) in a [256][64B] half
#define RDA(BUF, ROW) ((BUF) + ((ROW) << 6) + (cg ^ ((((ROW) >> 1) & 3) << 4)))

#define SFENCE __builtin_amdgcn_sched_barrier(0)
#define WAITV4 { SFENCE; asm volatile("s_waitcnt vmcnt(4)"); SFENCE; }
#define WAITV0 { SFENCE; asm volatile("s_waitcnt vmcnt(0)"); SFENCE; }
#define BARR   { SFENCE; __builtin_amdgcn_s_barrier(); SFENCE; }

    // prologue: tiles 0,1 -> bufs 0,1 (8 units). vmcnt(4) drains tile 0; tile 1's 4 may fly.
    STAGE(Ag, sm,                 0, (size_t)0); STAGE(Ag, sm,                 1, (size_t)0);
    STAGE(Bg, sm + 16384,         0, (size_t)0); STAGE(Bg, sm + 16384,         1, (size_t)0);
    STAGE(Ag, sm + 32768,         0, (size_t)64); STAGE(Ag, sm + 32768,         1, (size_t)64);
    STAGE(Bg, sm + 32768 + 16384, 0, (size_t)64); STAGE(Bg, sm + 32768 + 16384, 1, (size_t)64);
    WAITV4; BARR;

    for (int t = 0; t < NT; ++t) {
        const char* Ab = sm + ((t & 3) << 15);
        const char* Bb = Ab + 16384;
        char*       Nb = sm + (((t + 2) & 3) << 15);
        const bool  pf  = (t + 2 < NT);
        const size_t ktb = ((size_t)(t + 2)) << 6;   // (t+2)*32 bf16 = *64 bytes

        // reads for m0 cluster + all B (8 ds_read_b128)
        const int ar = wm * 128 + l16;
        #pragma unroll
        for (int mm = 0; mm < 4; ++mm) aq[mm] = *(const bf16x8*)RDA(Ab, ar + mm * 16);
        const int br = wn * 64 + l16;
        #pragma unroll
        for (int nn = 0; nn < 2; ++nn) {
            b0[nn] = *(const bf16x8*)RDA(Bb, br + nn * 16);
            b1[nn] = *(const bf16x8*)RDA(Bb, br + 32 + nn * 16);
        }
        if (pf) { STAGE(Ag, Nb, 0, ktb); STAGE(Ag, Nb, 1, ktb); }

        __builtin_amdgcn_s_setprio(1);
        #pragma unroll
        for (int mm = 0; mm < 4; ++mm)
            #pragma unroll
            for (int nn = 0; nn < 2; ++nn) {
                acc[mm][nn]     = MFMA16(aq[mm], b0[nn], acc[mm][nn]);
                acc[mm][2 + nn] = MFMA16(aq[mm], b1[nn], acc[mm][2 + nn]);
            }
        __builtin_amdgcn_s_setprio(0);

        // A-hi reads (4) complete under the m0 cluster above; aq overwrite is reg-WAR safe
        #pragma unroll
        for (int mm = 0; mm < 4; ++mm) aq[mm] = *(const bf16x8*)RDA(Ab, ar + 64 + mm * 16);
        if (pf) { STAGE(Bg, Nb + 16384, 0, ktb); STAGE(Bg, Nb + 16384, 1, ktb); }

        if (pf) { WAITV4; } else { WAITV0; }   // tile t+1 landed (newest 4 = this iter's stages)
        BARR;                                   // collective guarantee for next iter's reads

        __builtin_amdgcn_s_setprio(1);
        #pragma unroll
        for (int mm = 0; mm < 4; ++mm)
            #pragma unroll
            for (int nn = 0; nn < 2; ++nn) {
                acc[4 + mm][nn]     = MFMA16(aq[mm], b0[nn], acc[4 + mm][nn]);
                acc[4 + mm][2 + nn] = MFMA16(aq[mm], b1[nn], acc[4 + mm][2 + nn]);
            }
        __builtin_amdgcn_s_setprio(0);
    }
#undef STAGE
#undef RDA
#undef SFENCE
#undef WAITV4
#undef WAITV0
#undef BARR

    // epilogue: C/D frag layout col=lane&15, row=(lane>>4)*4+r  [m89/m91]
    const int rg = (lane >> 4) << 2;
    #pragma unroll
    for (int nq = 0; nq < 4; ++nq) {
        const int col = tn * 256 + wn * 64 + (nq >> 1) * 32 + (nq & 1) * 16 + l16;
        const float sc = scale[col];
        const float bi = bias[col];
        #pragma unroll
        for (int mq = 0; mq < 8; ++mq) {
            const int row0 = tm * 256 + wm * 128 + (mq >> 2) * 64 + (mq & 3) * 16 + rg;
            #pragma unroll
            for (int rr = 0; rr < 4; ++rr) {
                float v = acc[mq][nq][rr] * sc + bi;
                if (EPI == 0) {
                    float g = 0.5f * v * (1.0f + erff(v * 0.70710678118654752f));
                    ((unsigned short*)Cout)[(size_t)(row0 + rr) * 4096 + col] = f2bf(g);
                } else {
                    ((float*)Cout)[(size_t)(row0 + rr) * 4096 + col] = v;
                }
            }
        }
    }
}

extern "C" void kernel_launch(void* const* d_in, const int* in_sizes, int n_in,
                              void* d_out, int out_size, void* d_ws, size_t ws_size,
                              hipStream_t stream) {
    const float* x   = (const float*)d_in[0];
    const int*   w1q = (const int*)d_in[1];
    const float* s1  = (const float*)d_in[2];
    const float* b1  = (const float*)d_in[3];
    const int*   w2q = (const int*)d_in[4];
    const float* s2  = (const float*)d_in[5];
    const float* b2  = (const float*)d_in[6];
    float*       out = (float*)d_out;

    // allow 128 KiB dynamic LDS (idempotent, not a stream op)
    hipFuncSetAttribute((const void*)gemm4b<0>, hipFuncAttributeMaxDynamicSharedMemorySize, 131072);
    hipFuncSetAttribute((const void*)gemm4b<1>, hipFuncAttributeMaxDynamicSharedMemorySize, 131072);

    char* ws = (char*)d_ws;
    const size_t XBF  = (size_t)NROWS   * IN_DIM  * 2;
    const size_t W1BF = (size_t)HID_DIM * IN_DIM  * 2;
    const size_t W2BF = (size_t)OUT_DIM * HID_DIM * 2;
    const size_t FIXED = XBF + W1BF + W2BF;

    unsigned short* xbf  = (unsigned short*)ws;
    unsigned short* w1bf = (unsigned short*)(ws + XBF);
    unsigned short* w2bf = (unsigned short*)(ws + XBF + W1BF);
    unsigned short* hbuf = (unsigned short*)(ws + FIXED);

    {
        int nvx = NROWS * IN_DIM / 8;
        cvt_f32_bf16_k<<<(nvx + 255) / 256, 256, 0, stream>>>((const float4*)x, (uint4*)xbf, nvx);
        int nv1 = HID_DIM * IN_DIM / 8;
        cvt_i32_bf16_k<<<(nv1 + 255) / 256, 256, 0, stream>>>((const int4*)w1q, (uint4*)w1bf, nv1);
        int nv2 = OUT_DIM * HID_DIM / 8;
        cvt_i32_bf16_k<<<(nv2 + 255) / 256, 256, 0, stream>>>((const int4*)w2q, (uint4*)w2bf, nv2);
    }

    // chunk M (multiples of 256) so h fits in remaining workspace
    size_t avail = (ws_size > FIXED) ? (ws_size - FIXED) : 0;
    long rp = (long)(avail / ((size_t)HID_DIM * 2));
    rp = (rp / 256) * 256;
    if (rp > NROWS) rp = NROWS;
    if (rp < 256)   rp = 256;

    for (int r0 = 0; r0 < NROWS; r0 += (int)rp) {
        int rows = (int)(((long)(NROWS - r0) < rp) ? (NROWS - r0) : rp);
        dim3 g(NTN * (rows / 256));
        gemm4b<0><<<g, 512, 131072, stream>>>(xbf + (size_t)r0 * IN_DIM, w1bf, s1, b1,
                                              (void*)hbuf, IN_DIM);
        gemm4b<1><<<g, 512, 131072, stream>>>(hbuf, w2bf, s2, b2,
                                              (void*)(out + (size_t)r0 * OUT_DIM), HID_DIM);
    }
    (void)in_sizes; (void)n_in; (void)out_size;
}

// Round 14
// 801.679 us; speedup vs baseline: 1.0782x; 1.0782x over previous
//
#include <hip/hip_runtime.h>
#include <math.h>

// Problem constants (from reference)
#define NROWS 18432
#define IN_DIM 1024
#define HID_DIM 4096
#define OUT_DIM 4096
#define NTN 16    // 4096/256 column tiles (both layers)
#define BM  192   // row-tile: 18432/192=96 -> 96*16=1536 blocks = EXACTLY 6 rounds on 256 CUs

typedef __attribute__((ext_vector_type(8))) short bf16x8;
typedef __attribute__((ext_vector_type(4))) float f32x4;

typedef const __attribute__((address_space(1))) char gchar;
typedef __attribute__((address_space(3))) char lchar;

__device__ __forceinline__ unsigned short f2bf(float f) {
    union { float f; unsigned u; } v; v.f = f;
    unsigned r = v.u + 0x7fffu + ((v.u >> 16) & 1u);  // RNE
    return (unsigned short)(r >> 16);
}

__device__ __forceinline__ f32x4 MFMA16(bf16x8 a, bf16x8 b, f32x4 c) {
    return __builtin_amdgcn_mfma_f32_16x16x32_bf16(a, b, c, 0, 0, 0);
}

// ---------------- conversion kernels ----------------

__global__ void cvt_f32_bf16_k(const float4* __restrict__ in, uint4* __restrict__ out, int nvec) {
    int i = blockIdx.x * blockDim.x + threadIdx.x;
    if (i >= nvec) return;
    float4 a = in[2 * i], b = in[2 * i + 1];
    union { unsigned short s[8]; uint4 v; } o;
    o.s[0] = f2bf(a.x); o.s[1] = f2bf(a.y); o.s[2] = f2bf(a.z); o.s[3] = f2bf(a.w);
    o.s[4] = f2bf(b.x); o.s[5] = f2bf(b.y); o.s[6] = f2bf(b.z); o.s[7] = f2bf(b.w);
    out[i] = o.v;
}

// int8 values harness-materialized as int32; exact in bf16
__global__ void cvt_i32_bf16_k(const int4* __restrict__ in, uint4* __restrict__ out, int nvec) {
    int i = blockIdx.x * blockDim.x + threadIdx.x;
    if (i >= nvec) return;
    int4 a = in[2 * i], b = in[2 * i + 1];
    union { unsigned short s[8]; uint4 v; } o;
    o.s[0] = f2bf((float)a.x); o.s[1] = f2bf((float)a.y);
    o.s[2] = f2bf((float)a.z); o.s[3] = f2bf((float)a.w);
    o.s[4] = f2bf((float)b.x); o.s[5] = f2bf((float)b.y);
    o.s[6] = f2bf((float)b.z); o.s[7] = f2bf((float)b.w);
    out[i] = o.v;
}

// -------- 192x256 8-phase GEMM (R10 template, de-tailed grid), BK=64, 2 K-tiles/iter --------
// WHY BM=192: at BM=256 the grid is 1152 blocks = 4.5 rounds -> wall = 5 rounds with 128 CUs
// idle in round 5 (~11% waste). 1536 blocks = exactly 6 rounds, zero tail. In-loop structure is
// R10's m201 template verbatim (it measured at m201-class once round-packing is accounted for).
// 8 waves (2Mx4N), per-wave 96x64 (acc[6][4]). LDS: 2 bufs x 56KB {A 24KB (3x8KB units),
// B 32KB (4x8KB units)}; buf0 @0 (even tiles), buf1 @57344 (odd tiles).
// Stage units/phase: {P0:A(b)u01, P1:A(b)u2, P2:B(a+2)u01, P3:B(a+2)u23, P4:A(a+2)u01,
// P5:A(a+2)u2, P6:B(b+2)u01, P7:B(b+2)u23} = 14/iter. Waits: vmcnt(4) @P3 (11 outstanding,
// newest4 = B(a+2); drains A(b)+B(b)) and @P7 (newest4 = B(b+2); drains tile a+2) -- verified
// steady-state + prologue (11 issues, vmcnt(4)) + tail (v0 @P3, no stages/wait after).
// WAR: every stage target dead >=1 barrier earlier (A(a) dead P2, B(a) dead P1, A(b) dead P6,
// B(b) dead P5). All stages uniform 16B x 512 threads (per-wave vmcnt counts identical).
// Swizzle: slot (ks*4+cgi)^(l16&7) on reads; inverse on stage source (rule 21); 0-conflict.
// EPI==0: bf16 gelu(acc*sc+bi); EPI==1: f32 acc*sc+bi. Output row-stride hardcoded 4096.
template<int EPI>
__global__ __launch_bounds__(512, 2)
void gemm192(const unsigned short* __restrict__ A, const unsigned short* __restrict__ B,
             const float* __restrict__ scale, const float* __restrict__ bias,
             void* __restrict__ Cout, int K) {
    extern __shared__ __align__(16) char sm[];   // 114688 bytes dynamic

    const int tid  = threadIdx.x;
    const int lane = tid & 63;
    const int wid  = tid >> 6;
    const int wm   = wid >> 2, wn = wid & 3;

    // T1: bijective XCD swizzle (m204); nwg = 1536 (or chunked multiple of 16)
    const int nwg  = gridDim.x;
    const int q    = nwg >> 3, r = nwg & 7;
    const int xcd  = blockIdx.x & 7, bidx = blockIdx.x >> 3;
    const int swz  = xcd * q + (xcd < r ? xcd : r) + bidx;
    const int tm   = swz / NTN, tn = swz % NTN;

    const size_t rowbytes = (size_t)K * 2;
    const char* Ag = (const char*)A + (size_t)tm * BM * rowbytes;
    const char* Bg = (const char*)B + (size_t)tn * 256 * rowbytes;

    const int l16 = lane & 15;
    const int cgi = lane >> 4;
    const int sw  = l16 & 7;
    const int c0  = ((cgi       ^ sw) << 4);   // swizzled byte-slot, k-step 0
    const int c1  = (((4 | cgi) ^ sw) << 4);   // swizzled byte-slot, k-step 1

    f32x4  acc[6][4] = {};
    bf16x8 aq[3][2], bn0[2][2], bn1[2][2];

    const int NIT = K >> 7;   // iterations (2 K-tiles of 64 each)

// stage one 8KB unit UN of region at LDSOFF (A: UN 0-2 covers rows 0-191; B: UN 0-3 rows 0-255)
// LDS dest linear; global source pre-inverse-swizzled (rule 21).
#define STAGE(GB, LDSOFF, UN, TILE) { \
    const int po_ = ((UN) << 13) + (tid << 4); \
    const int pr_ = po_ >> 7; \
    const int pc_ = (po_ & 127) ^ ((pr_ & 7) << 4); \
    __builtin_amdgcn_global_load_lds( \
        (gchar*)((GB) + (size_t)pr_ * rowbytes + ((size_t)(TILE) << 7) + (size_t)pc_), \
        (lchar*)(sm + (LDSOFF) + po_), 16, 0, 0); \
}

// A frags for 48-row quadrant MH: rows wm*96 + MH*48 + mm*16 + l16 (row&7 == l16&7)
#define READ_A(BUFOFF, MH) { const char* Ab_ = sm + (BUFOFF); \
    _Pragma("unroll") for (int mm_ = 0; mm_ < 3; ++mm_) { \
        const int ro_ = (wm * 96 + (MH) * 48 + mm_ * 16 + l16) << 7; \
        aq[mm_][0] = *(const bf16x8*)(Ab_ + ro_ + c0); \
        aq[mm_][1] = *(const bf16x8*)(Ab_ + ro_ + c1); } }

// B frags for 32-col half NH of this wave's 64-col strip
#define READ_B(BUFOFF, NH, DST) { const char* Bb_ = sm + (BUFOFF) + 24576; \
    _Pragma("unroll") for (int nn_ = 0; nn_ < 2; ++nn_) { \
        const int ro_ = ((wn >> 1) * 128 + (wn & 1) * 64 + (NH) * 32 + nn_ * 16 + l16) << 7; \
        DST[nn_][0] = *(const bf16x8*)(Bb_ + ro_ + c0); \
        DST[nn_][1] = *(const bf16x8*)(Bb_ + ro_ + c1); } }

// one quadrant x K=64: 3 mm x 2 nn x 2 ks = 12 MFMA
#define MF(MH, NH, BQ) { __builtin_amdgcn_s_setprio(1); \
    _Pragma("unroll") for (int mm_ = 0; mm_ < 3; ++mm_) \
        _Pragma("unroll") for (int nn_ = 0; nn_ < 2; ++nn_) { \
            acc[(MH)*3+mm_][(NH)*2+nn_] = MFMA16(aq[mm_][0], BQ[nn_][0], acc[(MH)*3+mm_][(NH)*2+nn_]); \
            acc[(MH)*3+mm_][(NH)*2+nn_] = MFMA16(aq[mm_][1], BQ[nn_][1], acc[(MH)*3+mm_][(NH)*2+nn_]); } \
    __builtin_amdgcn_s_setprio(0); }

#define SFENCE __builtin_amdgcn_sched_barrier(0)
#define WAITV4 { SFENCE; asm volatile("s_waitcnt vmcnt(4)"); SFENCE; }
#define WAITV0 { SFENCE; asm volatile("s_waitcnt vmcnt(0)"); SFENCE; }
#define BARR   { SFENCE; __builtin_amdgcn_s_barrier(); SFENCE; }

#define BUF1 57344

    // prologue: A(0),B(0) -> buf0; B(1) -> buf1 (11 issues). vmcnt(4): A(0)+B(0) landed,
    // B(1)'s 4 may fly. A(1) staged at j=0 P0/P1.
    STAGE(Ag, 0,            0, 0); STAGE(Ag, 0,            1, 0); STAGE(Ag, 0,            2, 0);
    STAGE(Bg, 24576,        0, 0); STAGE(Bg, 24576,        1, 0);
    STAGE(Bg, 24576,        2, 0); STAGE(Bg, 24576,        3, 0);
    STAGE(Bg, BUF1 + 24576, 0, 1); STAGE(Bg, BUF1 + 24576, 1, 1);
    STAGE(Bg, BUF1 + 24576, 2, 1); STAGE(Bg, BUF1 + 24576, 3, 1);
    WAITV4; BARR;

    const int NT = K >> 6;
    for (int j = 0; j < NIT; ++j) {
        const int  t0 = 2 * j, t1 = 2 * j + 1;
        const bool lastj = (j == NIT - 1);   // note: (t0+2<NT) == (t1+2<NT) == !lastj

        // P0: (m0,n0) of tile t0 (buf0); stage A(t1)u0,u1 -> buf1
        READ_A(0, 0); READ_B(0, 0, bn0);
        STAGE(Ag, BUF1, 0, t1); STAGE(Ag, BUF1, 1, t1);
        BARR; MF(0, 0, bn0);
        // P1: (m0,n1); stage A(t1)u2
        READ_B(0, 1, bn1);
        STAGE(Ag, BUF1, 2, t1);
        BARR; MF(0, 1, bn1);
        // P2: (m1,n1); stage B(t0+2)u0,u1 -> buf0
        READ_A(0, 1);
        if (!lastj) { STAGE(Bg, 24576, 0, t0 + 2); STAGE(Bg, 24576, 1, t0 + 2); }
        BARR; MF(1, 1, bn1);
        // P3: (m1,n0); stage B(t0+2)u2,u3; counted wait #1 (drains A(t1)+B(t1))
        if (!lastj) { STAGE(Bg, 24576, 2, t0 + 2); STAGE(Bg, 24576, 3, t0 + 2); WAITV4; }
        else        { WAITV0; }
        BARR; MF(1, 0, bn0);
        // P4: (m0,n0) of tile t1 (buf1); stage A(t0+2)u0,u1 -> buf0
        READ_A(BUF1, 0); READ_B(BUF1, 0, bn0);
        if (!lastj) { STAGE(Ag, 0, 0, t0 + 2); STAGE(Ag, 0, 1, t0 + 2); }
        BARR; MF(0, 0, bn0);
        // P5: (m0,n1); stage A(t0+2)u2
        READ_B(BUF1, 1, bn1);
        if (!lastj) STAGE(Ag, 0, 2, t0 + 2);
        BARR; MF(0, 1, bn1);
        // P6: (m1,n1); stage B(t1+2)u0,u1 -> buf1
        READ_A(BUF1, 1);
        if (!lastj) { STAGE(Bg, BUF1 + 24576, 0, t1 + 2); STAGE(Bg, BUF1 + 24576, 1, t1 + 2); }
        BARR; MF(1, 1, bn1);
        // P7: (m1,n0); stage B(t1+2)u2,u3; counted wait #2 (drains tile t0+2)
        if (!lastj) { STAGE(Bg, BUF1 + 24576, 2, t1 + 2); STAGE(Bg, BUF1 + 24576, 3, t1 + 2);
                      WAITV4; }
        BARR; MF(1, 0, bn0);
    }
#undef STAGE
#undef READ_A
#undef READ_B
#undef MF
#undef SFENCE
#undef WAITV4
#undef WAITV0
#undef BARR
#undef BUF1

    // epilogue: C/D frag layout col=lane&15, row=(lane>>4)*4+r  [m89/m91]
    const int rg = (lane >> 4) << 2;
    #pragma unroll
    for (int nq = 0; nq < 4; ++nq) {
        const int col = tn * 256 + wn * 64 + (nq >> 1) * 32 + (nq & 1) * 16 + l16;
        const float sc = scale[col];
        const float bi = bias[col];
        #pragma unroll
        for (int mq = 0; mq < 6; ++mq) {
            const int row0 = tm * BM + wm * 96 + (mq / 3) * 48 + (mq % 3) * 16 + rg;
            #pragma unroll
            for (int rr = 0; rr < 4; ++rr) {
                float v = acc[mq][nq][rr] * sc + bi;
                if (EPI == 0) {
                    float g = 0.5f * v * (1.0f + erff(v * 0.70710678118654752f));
                    ((unsigned short*)Cout)[(size_t)(row0 + rr) * 4096 + col] = f2bf(g);
                } else {
                    ((float*)Cout)[(size_t)(row0 + rr) * 4096 + col] = v;
                }
            }
        }
    }
}

extern "C" void kernel_launch(void* const* d_in, const int* in_sizes, int n_in,
                              void* d_out, int out_size, void* d_ws, size_t ws_size,
                              hipStream_t stream) {
    const float* x   = (const float*)d_in[0];
    const int*   w1q = (const int*)d_in[1];
    const float* s1  = (const float*)d_in[2];
    const float* b1  = (const float*)d_in[3];
    const int*   w2q = (const int*)d_in[4];
    const float* s2  = (const float*)d_in[5];
    const float* b2  = (const float*)d_in[6];
    float*       out = (float*)d_out;

    // allow 112 KiB dynamic LDS (idempotent, not a stream op)
    hipFuncSetAttribute((const void*)gemm192<0>, hipFuncAttributeMaxDynamicSharedMemorySize, 114688);
    hipFuncSetAttribute((const void*)gemm192<1>, hipFuncAttributeMaxDynamicSharedMemorySize, 114688);

    char* ws = (char*)d_ws;
    const size_t XBF  = (size_t)NROWS   * IN_DIM  * 2;
    const size_t W1BF = (size_t)HID_DIM * IN_DIM  * 2;
    const size_t W2BF = (size_t)OUT_DIM * HID_DIM * 2;
    const size_t FIXED = XBF + W1BF + W2BF;

    unsigned short* xbf  = (unsigned short*)ws;
    unsigned short* w1bf = (unsigned short*)(ws + XBF);
    unsigned short* w2bf = (unsigned short*)(ws + XBF + W1BF);
    unsigned short* hbuf = (unsigned short*)(ws + FIXED);

    {
        int nvx = NROWS * IN_DIM / 8;
        cvt_f32_bf16_k<<<(nvx + 255) / 256, 256, 0, stream>>>((const float4*)x, (uint4*)xbf, nvx);
        int nv1 = HID_DIM * IN_DIM / 8;
        cvt_i32_bf16_k<<<(nv1 + 255) / 256, 256, 0, stream>>>((const int4*)w1q, (uint4*)w1bf, nv1);
        int nv2 = OUT_DIM * HID_DIM / 8;
        cvt_i32_bf16_k<<<(nv2 + 255) / 256, 256, 0, stream>>>((const int4*)w2q, (uint4*)w2bf, nv2);
    }

    // chunk M (multiples of BM) so h fits in remaining workspace
    size_t avail = (ws_size > FIXED) ? (ws_size - FIXED) : 0;
    long rp = (long)(avail / ((size_t)HID_DIM * 2));
    rp = (rp / BM) * BM;
    if (rp > NROWS) rp = NROWS;
    if (rp < BM)    rp = BM;

    for (int r0 = 0; r0 < NROWS; r0 += (int)rp) {
        int rows = (int)(((long)(NROWS - r0) < rp) ? (NROWS - r0) : rp);
        dim3 g(NTN * (rows / BM));
        gemm192<0><<<g, 512, 114688, stream>>>(xbf + (size_t)r0 * IN_DIM, w1bf, s1, b1,
                                               (void*)hbuf, IN_DIM);
        gemm192<1><<<g, 512, 114688, stream>>>(hbuf, w2bf, s2, b2,
                                               (void*)(out + (size_t)r0 * OUT_DIM), HID_DIM);
    }
    (void)in_sizes; (void)n_in; (void)out_size;
}